// Round 19
// baseline (151.243 us; speedup 1.0000x reference)
//
#include <hip/hip_runtime.h>

// AWQ int4 GEMM via INT8 MFMA + fixed-point rescale.
// M=2048 K=4096 N=11008 G=128.
// Math: xq=rint(x/sx[m]) i8; wq=q-z i8 EXACT; s_int=rint(sc*8192) (<=82).
//   out[m,n] = (sx[m]/8192) * sum_g s_int[g,n]*S_g,  S_g = sum_{k in g} xq*wq
// Ranges: |S_g|<=243840<2^23 (i24 ok); |s_int|<=82; |acc|<=6.4e8<2^31.
// R19 = R18 + full cross-macro B prefetch (both banks, ~700cy lead over use
// -> covers L3 ~500cy latency) + scconv folded into wdeq.
// Structure: A in LDS ring-4 (32KB), one __syncthreads per K128 macro.

#define MDIM 2048
#define KDIM 4096
#define NDIM 11008
#define NPC  1376
#define NT   64          // K/64 images
#define TILEB 8192       // bytes per K64 image: [128 rows][4 granules^swz][16 i8]

typedef int   int4v __attribute__((ext_vector_type(4)));

__device__ __forceinline__ int sext24(int v) {
    return (int)((unsigned)v << 8) >> 8;   // no-op in-range; enables v_mad_i32_i24 match
}

// ============ pass 1: fused row-max + x -> i8 K64-tile images ============
__global__ __launch_bounds__(256)
void xprep(const float* __restrict__ x, float* __restrict__ sx,
           char* __restrict__ xi) {
    const int wave = threadIdx.x >> 6, lane = threadIdx.x & 63;
    const int row  = blockIdx.x * 4 + wave;
    const float* xp = x + (size_t)row * KDIM + lane * 4;

    float m = 0.f;
    #pragma unroll
    for (int j = 0; j < 16; ++j) {
        const float4 v = *(const float4*)(xp + j * 256);
        m = fmaxf(m, fmaxf(fmaxf(fabsf(v.x), fabsf(v.y)),
                           fmaxf(fabsf(v.z), fabsf(v.w))));
    }
    #pragma unroll
    for (int off = 32; off; off >>= 1) m = fmaxf(m, __shfl_xor(m, off));
    if (lane == 0) sx[row] = m * (1.0f / 127.0f) * (1.0f / 8192.0f);  // pre-folded
    const float inv = 127.0f / m;

    const int r  = row & 127;
    const int mb = row >> 7;
    const int swz = (r >> 1) & 3;
    #pragma unroll
    for (int j = 0; j < 16; ++j) {
        const float4 f = *(const float4*)(xp + j * 256);
        const int i0 = __float2int_rn(f.x * inv), i1 = __float2int_rn(f.y * inv);
        const int i2 = __float2int_rn(f.z * inv), i3 = __float2int_rn(f.w * inv);
        const unsigned dw = (unsigned)(i0 & 255) | ((unsigned)(i1 & 255) << 8) |
                            ((unsigned)(i2 & 255) << 16) | ((unsigned)i3 << 24);
        const int k0 = j * 256 + lane * 4;
        const int tt = k0 >> 6;
        const int s  = (k0 >> 4) & 3;
        const size_t off = (size_t)(mb * NT + tt) * TILEB + r * 64
                         + (size_t)((s ^ swz) * 16) + (k0 & 15);
        *(unsigned*)(xi + off) = dw;
    }
}

// ============ pass 2: W -> i8 (q-z) images (EXACT) + scale fixed-point ============
__global__ __launch_bounds__(256)
void wdeq(const int* __restrict__ qw, const unsigned* __restrict__ qz,
          const float* __restrict__ sc, char* __restrict__ wi,
          int* __restrict__ scq)
{
    __shared__ char img[2 * TILEB];      // 16KB = 2 images

    const int t   = threadIdx.x;
    const int pc4 = t & 15;
    const int ko  = t >> 4;
    const int nb  = blockIdx.x;          // 0..85
    const int by  = blockIdx.y;          // 0..31 == quant group
    const int pcg = nb * 16 + pc4;

    // folded scconv: this block owns scq[by][nb*128 .. +128)
    if (t < 128)
        scq[(size_t)by * NDIM + nb * 128 + t] =
            __float2int_rn(sc[(size_t)by * NDIM + nb * 128 + t] * 8192.0f);

    const int* qp = qw + (size_t)(by * 128 + ko * 8) * NPC + pcg;
    unsigned w[8];
    #pragma unroll
    for (int r = 0; r < 8; ++r) w[r] = (unsigned)qp[(size_t)r * NPC];
    const unsigned rz = qz[(size_t)by * NPC + pcg];

    const int li = ko >> 3;
    const int sg = (ko & 7) >> 1;
    const int hf = ko & 1;
    const int SH[8] = {0, 16, 4, 20, 8, 24, 12, 28};

    #pragma unroll
    for (int mm = 0; mm < 8; ++mm) {
        const int m  = (mm + pc4) & 7;
        const int sh = SH[m];
        const unsigned z = (rz >> sh) & 15u;
        const unsigned bias = (128u - z) * 0x01010101u;
        const unsigned qlo = ((w[0] >> sh) & 15u) | (((w[1] >> sh) & 15u) << 8) |
                             (((w[2] >> sh) & 15u) << 16) | (((w[3] >> sh) & 15u) << 24);
        const unsigned qhi = ((w[4] >> sh) & 15u) | (((w[5] >> sh) & 15u) << 8) |
                             (((w[6] >> sh) & 15u) << 16) | (((w[7] >> sh) & 15u) << 24);
        uint2 b;
        b.x = (qlo + bias) ^ 0x80808080u;
        b.y = (qhi + bias) ^ 0x80808080u;
        const int n = pc4 * 8 + m;
        *(uint2*)(img + li * TILEB + n * 64 + ((sg ^ ((n >> 1) & 3)) * 16) + hf * 8) = b;
    }
    __syncthreads();

    char* dst = wi + (size_t)(nb * NT + by * 2) * TILEB;
    #pragma unroll
    for (int i = 0; i < 4; ++i) {
        const int idx = i * 256 + t;
        *(uint4*)(dst + idx * 16) = *(const uint4*)(img + idx * 16);
    }
}

// ============ pass 3: A-in-LDS(ring4) + fully-pipelined-B i8 GEMM ============
__global__ __launch_bounds__(256, 3)
void awq_gemm15(const char* __restrict__ xi, const char* __restrict__ wi,
                const int* __restrict__ scq, const float* __restrict__ sx,
                float* __restrict__ out)
{
    __shared__ char As[4][TILEB];        // 32KB: ring of 4 K64 A-images

    const int t    = threadIdx.x;
    const int lane = t & 63;
    const int wave = t >> 6;
    const int WR   = wave >> 1;          // 0..1
    const int WC   = wave & 1;           // 0..1
    const int l15  = lane & 15;
    const int soff = ((lane >> 4) ^ ((l15 >> 1) & 3)) * 16;   // byte offset

    const int mb = blockIdx.x;           // 0..15
    const int nb = blockIdx.y;           // 0..85

    const char* aimg = xi + (size_t)mb * NT * TILEB + t * 16;
    const char* pb = wi + (size_t)nb * NT * TILEB + (WC * 64 + l15) * 64 + soff;
    const int* sptr = scq + nb * 128 + WC * 64 + l15;

    int accq[4][4][4];                   // exact i32: sum_g s_int*S_g
    #pragma unroll
    for (int i = 0; i < 4; ++i)
        #pragma unroll
        for (int j = 0; j < 4; ++j)
            #pragma unroll
            for (int e = 0; e < 4; ++e)
                accq[i][j][e] = 0;

    const int4v ZZ = (int4v){0, 0, 0, 0};

#define GLL(SRC, DST) __builtin_amdgcn_global_load_lds(                        \
    (const __attribute__((address_space(1))) void*)(SRC),                     \
    (__attribute__((address_space(3))) void*)(DST), 16, 0, 0)

#define ISSUE_A(TT) do {                                                      \
    const int S_ = (TT) & 3;                                                  \
    const char* a_ = aimg + (size_t)(TT) * TILEB;                             \
    GLL(a_,        &As[S_][t * 16]);                                          \
    GLL(a_ + 4096, &As[S_][4096 + t * 16]);                                   \
} while (0)

#define LD_A(S_, I) (*(const int4v*)&As[S_][(WR * 64 + (I) * 16 + l15) * 64 + soff])

    // current macro B banks (both sub-tiles) + next macro (prefetched)
    int4v b0, b1, b2, b3, c0, c1, c2, c3;
    int4v nb0, nb1, nb2, nb3, nc0, nc1, nc2, nc3;
    int s0, s1, s2, s3;

    // prologue: macro 0's B fully loaded; A images 0,1 in flight
    ISSUE_A(0);
    ISSUE_A(1);
    b0 = *(const int4v*)(pb);
    b1 = *(const int4v*)(pb + 1024);
    b2 = *(const int4v*)(pb + 2048);
    b3 = *(const int4v*)(pb + 3072);
    {
        const char* bC = pb + TILEB;
        c0 = *(const int4v*)(bC);
        c1 = *(const int4v*)(bC + 1024);
        c2 = *(const int4v*)(bC + 2048);
        c3 = *(const int4v*)(bC + 3072);
    }
    s0 = sptr[0]; s1 = sptr[16]; s2 = sptr[32]; s3 = sptr[48];
    __syncthreads();

    #pragma unroll 1
    for (int g = 0; g < 32; ++g) {
        const int sa0 = (2 * g) & 3, sa1 = (2 * g + 1) & 3;

        int u0, u1, u2, u3;
        if (g < 31) {
            // full cross-macro prefetch: next macro's BOTH B banks + A + scales
            const char* bN0 = pb + (size_t)(2 * g + 2) * TILEB;
            const char* bN1 = bN0 + TILEB;
            nb0 = *(const int4v*)(bN0);
            nb1 = *(const int4v*)(bN0 + 1024);
            nb2 = *(const int4v*)(bN0 + 2048);
            nb3 = *(const int4v*)(bN0 + 3072);
            nc0 = *(const int4v*)(bN1);
            nc1 = *(const int4v*)(bN1 + 1024);
            nc2 = *(const int4v*)(bN1 + 2048);
            nc3 = *(const int4v*)(bN1 + 3072);
            ISSUE_A(2 * g + 2);
            ISSUE_A(2 * g + 3);
            const int* sp = sptr + (size_t)(g + 1) * NDIM;
            u0 = sp[0]; u1 = sp[16]; u2 = sp[32]; u3 = sp[48];
        } else { u0 = u1 = u2 = u3 = 0; }

        const int ss0 = sext24(s0), ss1 = sext24(s1);
        const int ss2 = sext24(s2), ss3 = sext24(s3);

        // per-A-fragment: fresh MFMA -> acc MFMA -> i24-mad rescale
        #pragma unroll
        for (int i = 0; i < 4; ++i) {
            const int4v a0 = LD_A(sa0, i);
            const int4v a1 = LD_A(sa1, i);
            int4v t0 = __builtin_amdgcn_mfma_i32_16x16x64_i8(a0, b0, ZZ, 0, 0, 0);
            int4v t1 = __builtin_amdgcn_mfma_i32_16x16x64_i8(a0, b1, ZZ, 0, 0, 0);
            int4v t2 = __builtin_amdgcn_mfma_i32_16x16x64_i8(a0, b2, ZZ, 0, 0, 0);
            int4v t3 = __builtin_amdgcn_mfma_i32_16x16x64_i8(a0, b3, ZZ, 0, 0, 0);
            t0 = __builtin_amdgcn_mfma_i32_16x16x64_i8(a1, c0, t0, 0, 0, 0);
            t1 = __builtin_amdgcn_mfma_i32_16x16x64_i8(a1, c1, t1, 0, 0, 0);
            t2 = __builtin_amdgcn_mfma_i32_16x16x64_i8(a1, c2, t2, 0, 0, 0);
            t3 = __builtin_amdgcn_mfma_i32_16x16x64_i8(a1, c3, t3, 0, 0, 0);
            #pragma unroll
            for (int e = 0; e < 4; ++e) {
                accq[i][0][e] += ss0 * sext24(t0[e]);
                accq[i][1][e] += ss1 * sext24(t1[e]);
                accq[i][2][e] += ss2 * sext24(t2[e]);
                accq[i][3][e] += ss3 * sext24(t3[e]);
            }
        }
        b0 = nb0; b1 = nb1; b2 = nb2; b3 = nb3;
        c0 = nc0; c1 = nc1; c2 = nc2; c3 = nc3;
        s0 = u0; s1 = u1; s2 = u2; s3 = u3;

        __syncthreads();                 // drain A prefetch + publish slots
    }

    // ---- epilogue: out = accq * (sx[row]/8192)  (sx pre-folded) ----
    const int m0 = mb * 128, n0 = nb * 128;
    const int crow = (lane >> 4) * 4;
    #pragma unroll
    for (int i = 0; i < 4; ++i) {
        const float4 sq = *(const float4*)&sx[m0 + WR * 64 + i * 16 + crow];
        float sqa[4] = {sq.x, sq.y, sq.z, sq.w};
        #pragma unroll
        for (int j = 0; j < 4; ++j) {
            const size_t base =
                (size_t)(m0 + WR * 64 + i * 16 + crow) * NDIM +
                (n0 + WC * 64 + j * 16 + l15);
            #pragma unroll
            for (int e = 0; e < 4; ++e)
                out[base + (size_t)e * NDIM] = (float)accq[i][j][e] * sqa[e];
        }
    }
#undef GLL
#undef ISSUE_A
#undef LD_A
}

extern "C" void kernel_launch(void* const* d_in, const int* in_sizes, int n_in,
                              void* d_out, int out_size, void* d_ws, size_t ws_size,
                              hipStream_t stream) {
    const float*    x  = (const float*)d_in[0];
    const int*      qw = (const int*)d_in[1];
    const unsigned* qz = (const unsigned*)d_in[2];
    const float*    sc = (const float*)d_in[3];
    float* out = (float*)d_out;

    const size_t SXB  = 16384;                       // sx[2048] (pre-folded /8192)
    const size_t XIB  = (size_t)16 * NT * TILEB;     // 8.4 MB i8 x images
    const size_t WIB  = (size_t)86 * NT * TILEB;     // 45.1 MB i8 W images
    const size_t SCQB = (size_t)32 * NDIM * 4;       // 1.41 MB fixed-point scales
    if (ws_size < SXB + XIB + WIB + SCQB) return;

    float* sx  = (float*)d_ws;
    char*  xi  = (char*)d_ws + SXB;
    char*  wi  = xi + XIB;
    int*   scq = (int*)(wi + WIB);

    xprep<<<512, 256, 0, stream>>>(x, sx, xi);
    wdeq<<<dim3(86, 32), 256, 0, stream>>>(qw, qz, sc, wi, scq);
    awq_gemm15<<<dim3(16, 86), 256, 0, stream>>>(xi, wi, scq, sx, out);
}